// Round 6
// baseline (166.326 us; speedup 1.0000x reference)
//
#include <hip/hip_runtime.h>

// LoRA fused forward: out[b,s,o] = 2.0 * sum_r ( sum_i x[b,s,i]*A[idx[b],i,r] ) * Bm[idx[b],r,o]
// x [16,2048,2048] f32, idx [16], A [16,2048,8] f32, Bm [16,8,2048] f32.
// v6: max-TLP config. SC=16 rows/block, GR=2 (minimal VGPR: v4 shape hit
//     exactly 64 -> 8 waves/SIMD possible), grid 2048 = 8 blocks/CU -> up to
//     32 waves/CU resident. One barrier. Plain (non-NT) stores — NT bought
//     nothing in R3-R5 A/B. Pass1 pure read stream, pass2 pure write stream.

typedef float f32x4 __attribute__((ext_vector_type(4)));

constexpr int IN_DIM  = 2048;
constexpr int OUT_DIM = 2048;
constexpr int RANK    = 8;
constexpr int S_LEN   = 2048;
constexpr int B_SZ    = 16;
constexpr int SC      = 16;          // rows per block
constexpr int GR      = 2;           // rows per pass1 group
constexpr int NG      = SC / GR;     // 8 groups
constexpr float SCALING = 2.0f;

__global__ __launch_bounds__(256) void lora_v6(
    const float* __restrict__ x,
    const int*   __restrict__ idx,
    const float* __restrict__ la,
    const float* __restrict__ lb,
    float*       __restrict__ out)
{
    const int t    = threadIdx.x;
    const int lane = t & 63;
    const int wave = t >> 6;

    constexpr int BPB = S_LEN / SC;   // 128 blocks per batch element
    const int b   = blockIdx.x / BPB;
    const int s0  = (blockIdx.x % BPB) * SC;
    const int pid = idx[b];

    // Partials: [row][wave][r], pre-scaled by SCALING in pass1. 2 KB.
    __shared__ float red[SC][4][RANK];

    // Thread's input coverage: i = t*4..t*4+3 and i = 1024+t*4..1024+t*4+3.
    float a_reg[8][RANK];
    {
        const float* ap0 = la + ((size_t)pid * IN_DIM + (size_t)t * 4) * RANK;
        const float* ap1 = ap0 + (size_t)1024 * RANK;
        #pragma unroll
        for (int j = 0; j < 4; ++j) {
            float4 v0 = *reinterpret_cast<const float4*>(ap0 + j * RANK);
            float4 v1 = *reinterpret_cast<const float4*>(ap0 + j * RANK + 4);
            a_reg[j][0]=v0.x; a_reg[j][1]=v0.y; a_reg[j][2]=v0.z; a_reg[j][3]=v0.w;
            a_reg[j][4]=v1.x; a_reg[j][5]=v1.y; a_reg[j][6]=v1.z; a_reg[j][7]=v1.w;
            float4 w0 = *reinterpret_cast<const float4*>(ap1 + j * RANK);
            float4 w1 = *reinterpret_cast<const float4*>(ap1 + j * RANK + 4);
            a_reg[4+j][0]=w0.x; a_reg[4+j][1]=w0.y; a_reg[4+j][2]=w0.z; a_reg[4+j][3]=w0.w;
            a_reg[4+j][4]=w1.x; a_reg[4+j][5]=w1.y; a_reg[4+j][6]=w1.z; a_reg[4+j][7]=w1.w;
        }
    }

    const float* xbase = x + ((size_t)b * S_LEN + s0) * IN_DIM;

    // ---------------- PASS 1: partial dot-products, no barriers ----------------
    float4 xbA[GR][2], xbB[GR][2];

    auto load_group = [&](int g, float4 (&dst)[GR][2]) {
        #pragma unroll
        for (int row = 0; row < GR; ++row) {
            const float* xr = xbase + (size_t)(g * GR + row) * IN_DIM;
            dst[row][0] = *reinterpret_cast<const float4*>(xr + t * 4);
            dst[row][1] = *reinterpret_cast<const float4*>(xr + 1024 + t * 4);
        }
    };

    auto do_group = [&](int g, float4 (&cur)[GR][2], float4 (&nxt)[GR][2]) {
        if (g + 1 < NG) load_group(g + 1, nxt);

        float acc[GR][RANK];
        #pragma unroll
        for (int row = 0; row < GR; ++row) {
            #pragma unroll
            for (int r = 0; r < RANK; ++r) acc[row][r] = 0.0f;
            float4 xlo = cur[row][0];
            float4 xhi = cur[row][1];
            float xv[8] = {xlo.x, xlo.y, xlo.z, xlo.w, xhi.x, xhi.y, xhi.z, xhi.w};
            #pragma unroll
            for (int j = 0; j < 8; ++j)
                #pragma unroll
                for (int r = 0; r < RANK; ++r)
                    acc[row][r] = fmaf(xv[j], a_reg[j][r], acc[row][r]);
        }

        // Merge-exchange reduce: 16 values (2 rows x 8 ranks) over 64 lanes.
        float m4[GR][4];
        {
            const bool hi = lane & 1;
            #pragma unroll
            for (int row = 0; row < GR; ++row)
                #pragma unroll
                for (int j = 0; j < 4; ++j) {
                    float snd = hi ? acc[row][j] : acc[row][j + 4];
                    float kp  = hi ? acc[row][j + 4] : acc[row][j];
                    m4[row][j] = kp + __shfl_xor(snd, 1);
                }
        }
        float m2[GR][2];
        {
            const bool hi = lane & 2;
            #pragma unroll
            for (int row = 0; row < GR; ++row)
                #pragma unroll
                for (int j = 0; j < 2; ++j) {
                    float snd = hi ? m4[row][j] : m4[row][j + 2];
                    float kp  = hi ? m4[row][j + 2] : m4[row][j];
                    m2[row][j] = kp + __shfl_xor(snd, 2);
                }
        }
        float m1[GR];
        {
            const bool hi = lane & 4;
            #pragma unroll
            for (int row = 0; row < GR; ++row) {
                float snd = hi ? m2[row][0] : m2[row][1];
                float kp  = hi ? m2[row][1] : m2[row][0];
                m1[row] = kp + __shfl_xor(snd, 4);
            }
        }
        float w1;
        {
            const bool hi = lane & 8;
            float snd = hi ? m1[0] : m1[1];
            float kp  = hi ? m1[1] : m1[0];
            w1 = kp + __shfl_xor(snd, 8);
        }
        w1 += __shfl_xor(w1, 16);
        w1 += __shfl_xor(w1, 32);

        const int rOf   = ((lane & 1) << 2) | (lane & 2) | ((lane >> 2) & 1);
        const int rowOf = (lane >> 3) & 1;
        if (lane < 16) red[g * GR + rowOf][wave][rOf] = w1 * SCALING;
    };

    load_group(0, xbA);
    #pragma unroll
    for (int gg = 0; gg < NG; gg += 2) {
        do_group(gg,     xbA, xbB);
        do_group(gg + 1, xbB, xbA);
    }

    __syncthreads();   // THE barrier

    // ---------------- PASS 2: combine + expand + store, no barriers ----------------
    float b_reg[RANK][8];
    {
        const float* bp = lb + (size_t)pid * RANK * OUT_DIM + (size_t)t * 4;
        #pragma unroll
        for (int r = 0; r < RANK; ++r) {
            float4 v0 = *reinterpret_cast<const float4*>(bp + (size_t)r * OUT_DIM);
            float4 v1 = *reinterpret_cast<const float4*>(bp + (size_t)r * OUT_DIM + 1024);
            b_reg[r][0]=v0.x; b_reg[r][1]=v0.y; b_reg[r][2]=v0.z; b_reg[r][3]=v0.w;
            b_reg[r][4]=v1.x; b_reg[r][5]=v1.y; b_reg[r][6]=v1.z; b_reg[r][7]=v1.w;
        }
    }

    float* obase = out + ((size_t)b * S_LEN + s0) * OUT_DIM;

    #pragma unroll 2
    for (int row = 0; row < SC; ++row) {
        float4 lo = *reinterpret_cast<const float4*>(&red[row][0][0]);
        float4 hi = *reinterpret_cast<const float4*>(&red[row][0][4]);
        #pragma unroll
        for (int w = 1; w < 4; ++w) {
            float4 l2 = *reinterpret_cast<const float4*>(&red[row][w][0]);
            float4 h2 = *reinterpret_cast<const float4*>(&red[row][w][4]);
            lo.x += l2.x; lo.y += l2.y; lo.z += l2.z; lo.w += l2.w;
            hi.x += h2.x; hi.y += h2.y; hi.z += h2.z; hi.w += h2.w;
        }
        float xs[RANK] = {lo.x, lo.y, lo.z, lo.w, hi.x, hi.y, hi.z, hi.w};

        float ov[8];
        #pragma unroll
        for (int j = 0; j < 8; ++j) ov[j] = 0.0f;
        #pragma unroll
        for (int r = 0; r < RANK; ++r)
            #pragma unroll
            for (int j = 0; j < 8; ++j)
                ov[j] = fmaf(xs[r], b_reg[r][j], ov[j]);

        float* orow = obase + (size_t)row * OUT_DIM;
        *reinterpret_cast<float4*>(orow + t * 4)        = make_float4(ov[0], ov[1], ov[2], ov[3]);
        *reinterpret_cast<float4*>(orow + 1024 + t * 4) = make_float4(ov[4], ov[5], ov[6], ov[7]);
    }
}

extern "C" void kernel_launch(void* const* d_in, const int* in_sizes, int n_in,
                              void* d_out, int out_size, void* d_ws, size_t ws_size,
                              hipStream_t stream) {
    const float* x   = (const float*)d_in[0];
    const int*   idx = (const int*)  d_in[1];
    const float* la  = (const float*)d_in[2];
    const float* lb  = (const float*)d_in[3];
    float* out = (float*)d_out;

    dim3 grid(B_SZ * (S_LEN / SC));  // 2048 blocks, 16 rows each, 8 blocks/CU
    lora_v6<<<grid, 256, 0, stream>>>(x, idx, la, lb, out);
}

// Round 7
// 93.759 us; speedup vs baseline: 1.7740x; 1.7740x over previous
//
#include <hip/hip_runtime.h>

// LoRA fused forward: out[b,s,o] = 2.0 * sum_r ( sum_i x[b,s,i]*A[idx[b],i,r] ) * Bm[idx[b],r,o]
// x [16,2048,2048] f32, idx [16], A [16,2048,8] f32, Bm [16,8,2048] f32.
// v7 == v5 (best measured: 96.5 us, 85% of copy-bench fabric rate on the
// mandatory 512 MB). One barrier, GR=4 prefetch, SC=32, grid 1024 = 4 blk/CU.
// v6's regression root-cause: unpinned regalloc -> VGPR 116; v5's shape is
// the sweet spot (VGPR 76, 4 waves/SIMD).

typedef float f32x4 __attribute__((ext_vector_type(4)));

constexpr int IN_DIM  = 2048;
constexpr int OUT_DIM = 2048;
constexpr int RANK    = 8;
constexpr int S_LEN   = 2048;
constexpr int B_SZ    = 16;
constexpr int SC      = 32;          // rows per block
constexpr int GR      = 4;           // rows per pass1 group
constexpr int NG      = SC / GR;     // 8 groups
constexpr float SCALING = 2.0f;

__global__ __launch_bounds__(256) void lora_v7(
    const float* __restrict__ x,
    const int*   __restrict__ idx,
    const float* __restrict__ la,
    const float* __restrict__ lb,
    float*       __restrict__ out)
{
    const int t    = threadIdx.x;
    const int lane = t & 63;
    const int wave = t >> 6;

    constexpr int BPB = S_LEN / SC;   // 64 blocks per batch element
    const int b   = blockIdx.x / BPB;
    const int s0  = (blockIdx.x % BPB) * SC;
    const int pid = idx[b];

    // Partials: [row][wave][r], pre-scaled by SCALING in pass1. 4 KB.
    __shared__ float red[SC][4][RANK];

    // Thread's input coverage: i = t*4..t*4+3 and i = 1024+t*4..1024+t*4+3.
    float a_reg[8][RANK];
    {
        const float* ap0 = la + ((size_t)pid * IN_DIM + (size_t)t * 4) * RANK;
        const float* ap1 = ap0 + (size_t)1024 * RANK;
        #pragma unroll
        for (int j = 0; j < 4; ++j) {
            float4 v0 = *reinterpret_cast<const float4*>(ap0 + j * RANK);
            float4 v1 = *reinterpret_cast<const float4*>(ap0 + j * RANK + 4);
            a_reg[j][0]=v0.x; a_reg[j][1]=v0.y; a_reg[j][2]=v0.z; a_reg[j][3]=v0.w;
            a_reg[j][4]=v1.x; a_reg[j][5]=v1.y; a_reg[j][6]=v1.z; a_reg[j][7]=v1.w;
            float4 w0 = *reinterpret_cast<const float4*>(ap1 + j * RANK);
            float4 w1 = *reinterpret_cast<const float4*>(ap1 + j * RANK + 4);
            a_reg[4+j][0]=w0.x; a_reg[4+j][1]=w0.y; a_reg[4+j][2]=w0.z; a_reg[4+j][3]=w0.w;
            a_reg[4+j][4]=w1.x; a_reg[4+j][5]=w1.y; a_reg[4+j][6]=w1.z; a_reg[4+j][7]=w1.w;
        }
    }

    const float* xbase = x + ((size_t)b * S_LEN + s0) * IN_DIM;

    // ---------------- PASS 1: partial dot-products, no barriers ----------------
    float4 xbA[GR][2], xbB[GR][2];

    auto load_group = [&](int g, float4 (&dst)[GR][2]) {
        #pragma unroll
        for (int row = 0; row < GR; ++row) {
            const float* xr = xbase + (size_t)(g * GR + row) * IN_DIM;
            dst[row][0] = *reinterpret_cast<const float4*>(xr + t * 4);
            dst[row][1] = *reinterpret_cast<const float4*>(xr + 1024 + t * 4);
        }
    };

    auto do_group = [&](int g, float4 (&cur)[GR][2], float4 (&nxt)[GR][2]) {
        if (g + 1 < NG) load_group(g + 1, nxt);

        float acc[GR][RANK];
        #pragma unroll
        for (int row = 0; row < GR; ++row) {
            #pragma unroll
            for (int r = 0; r < RANK; ++r) acc[row][r] = 0.0f;
            float4 xlo = cur[row][0];
            float4 xhi = cur[row][1];
            float xv[8] = {xlo.x, xlo.y, xlo.z, xlo.w, xhi.x, xhi.y, xhi.z, xhi.w};
            #pragma unroll
            for (int j = 0; j < 8; ++j)
                #pragma unroll
                for (int r = 0; r < RANK; ++r)
                    acc[row][r] = fmaf(xv[j], a_reg[j][r], acc[row][r]);
        }

        // Merge-exchange reduce: 32 values (4 rows x 8 ranks) over 64 lanes.
        // Final: lane holds r = 4b0+2b1+b2, row = 2b3+b4 (b = lane bits).
        float m4[GR][4];
        {
            const bool hi = lane & 1;
            #pragma unroll
            for (int row = 0; row < GR; ++row)
                #pragma unroll
                for (int j = 0; j < 4; ++j) {
                    float snd = hi ? acc[row][j] : acc[row][j + 4];
                    float kp  = hi ? acc[row][j + 4] : acc[row][j];
                    m4[row][j] = kp + __shfl_xor(snd, 1);
                }
        }
        float m2[GR][2];
        {
            const bool hi = lane & 2;
            #pragma unroll
            for (int row = 0; row < GR; ++row)
                #pragma unroll
                for (int j = 0; j < 2; ++j) {
                    float snd = hi ? m4[row][j] : m4[row][j + 2];
                    float kp  = hi ? m4[row][j + 2] : m4[row][j];
                    m2[row][j] = kp + __shfl_xor(snd, 2);
                }
        }
        float m1[GR];
        {
            const bool hi = lane & 4;
            #pragma unroll
            for (int row = 0; row < GR; ++row) {
                float snd = hi ? m2[row][0] : m2[row][1];
                float kp  = hi ? m2[row][1] : m2[row][0];
                m1[row] = kp + __shfl_xor(snd, 4);
            }
        }
        float w2[2];
        {
            const bool hi = lane & 8;
            #pragma unroll
            for (int j = 0; j < 2; ++j) {
                float snd = hi ? m1[j] : m1[j + 2];
                float kp  = hi ? m1[j + 2] : m1[j];
                w2[j] = kp + __shfl_xor(snd, 8);
            }
        }
        float w1;
        {
            const bool hi = lane & 16;
            float snd = hi ? w2[0] : w2[1];
            float kp  = hi ? w2[1] : w2[0];
            w1 = kp + __shfl_xor(snd, 16);
        }
        w1 += __shfl_xor(w1, 32);

        const int rOf   = ((lane & 1) << 2) | (lane & 2) | ((lane >> 2) & 1);
        const int rowOf = ((lane >> 2) & 2) | ((lane >> 4) & 1);
        if (lane < 32) red[g * GR + rowOf][wave][rOf] = w1 * SCALING;
    };

    load_group(0, xbA);
    #pragma unroll
    for (int gg = 0; gg < NG; gg += 2) {
        do_group(gg,     xbA, xbB);
        do_group(gg + 1, xbB, xbA);
    }

    __syncthreads();   // THE barrier

    // ---------------- PASS 2: combine + expand + store, no barriers ----------------
    float b_reg[RANK][8];
    {
        const float* bp = lb + (size_t)pid * RANK * OUT_DIM + (size_t)t * 4;
        #pragma unroll
        for (int r = 0; r < RANK; ++r) {
            float4 v0 = *reinterpret_cast<const float4*>(bp + (size_t)r * OUT_DIM);
            float4 v1 = *reinterpret_cast<const float4*>(bp + (size_t)r * OUT_DIM + 1024);
            b_reg[r][0]=v0.x; b_reg[r][1]=v0.y; b_reg[r][2]=v0.z; b_reg[r][3]=v0.w;
            b_reg[r][4]=v1.x; b_reg[r][5]=v1.y; b_reg[r][6]=v1.z; b_reg[r][7]=v1.w;
        }
    }

    float* obase = out + ((size_t)b * S_LEN + s0) * OUT_DIM;

    #pragma unroll 2
    for (int row = 0; row < SC; ++row) {
        float4 lo = *reinterpret_cast<const float4*>(&red[row][0][0]);
        float4 hi = *reinterpret_cast<const float4*>(&red[row][0][4]);
        #pragma unroll
        for (int w = 1; w < 4; ++w) {
            float4 l2 = *reinterpret_cast<const float4*>(&red[row][w][0]);
            float4 h2 = *reinterpret_cast<const float4*>(&red[row][w][4]);
            lo.x += l2.x; lo.y += l2.y; lo.z += l2.z; lo.w += l2.w;
            hi.x += h2.x; hi.y += h2.y; hi.z += h2.z; hi.w += h2.w;
        }
        float xs[RANK] = {lo.x, lo.y, lo.z, lo.w, hi.x, hi.y, hi.z, hi.w};

        float ov[8];
        #pragma unroll
        for (int j = 0; j < 8; ++j) ov[j] = 0.0f;
        #pragma unroll
        for (int r = 0; r < RANK; ++r)
            #pragma unroll
            for (int j = 0; j < 8; ++j)
                ov[j] = fmaf(xs[r], b_reg[r][j], ov[j]);

        float* orow = obase + (size_t)row * OUT_DIM;
        f32x4 o0 = {ov[0], ov[1], ov[2], ov[3]};
        f32x4 o1 = {ov[4], ov[5], ov[6], ov[7]};
        __builtin_nontemporal_store(o0, reinterpret_cast<f32x4*>(orow + t * 4));
        __builtin_nontemporal_store(o1, reinterpret_cast<f32x4*>(orow + 1024 + t * 4));
    }
}

extern "C" void kernel_launch(void* const* d_in, const int* in_sizes, int n_in,
                              void* d_out, int out_size, void* d_ws, size_t ws_size,
                              hipStream_t stream) {
    const float* x   = (const float*)d_in[0];
    const int*   idx = (const int*)  d_in[1];
    const float* la  = (const float*)d_in[2];
    const float* lb  = (const float*)d_in[3];
    float* out = (float*)d_out;

    dim3 grid(B_SZ * (S_LEN / SC));  // 1024 blocks, 32 rows each, 4 blocks/CU
    lora_v7<<<grid, 256, 0, stream>>>(x, idx, la, lb, out);
}